// Round 4
// baseline (546.739 us; speedup 1.0000x reference)
//
#include <hip/hip_runtime.h>
#include <hip/hip_bf16.h>
#include <math.h>

#define V_NODES 262144
#define NGRAPH  4096
#define FD      256
#define TSTEPS  2
#define GP      16     // graphs per k_steps block (one wave per graph)
#define SB      1024   // k_steps block size: 16 waves
#define RS      264    // padded LDS row stride (u16) — 528B = 33*16B, +4-bank skew
#define EWCAP   2560   // max nodes per GP-graph block (mean 1024, sigma ~32)

typedef unsigned short u16;
typedef __attribute__((ext_vector_type(8))) short short8;
typedef __attribute__((ext_vector_type(4))) float f32x4;

__device__ __forceinline__ float bf2f(u16 u) {
  union { unsigned int i; float f; } x; x.i = ((unsigned int)u) << 16; return x.f;
}
__device__ __forceinline__ u16 f2bf(float f) {
  union { unsigned int i; float f; } x; x.f = f;
  unsigned int r = x.i + 0x7FFFu + ((x.i >> 16) & 1u);
  return (u16)(r >> 16);
}
__device__ __forceinline__ unsigned int pkbf(float a, float b) {
  return (unsigned int)f2bf(a) | ((unsigned int)f2bf(b) << 16);
}
__device__ __forceinline__ float softplus2(float x) {
  return fmaxf(x, 0.0f) + log1pf(__expf(-fabsf(x))) - 0.69314718056f;
}
__device__ __forceinline__ float dot4(const float4 x, const float4 w) {
  return fmaf(x.x, w.x, fmaf(x.y, w.y, fmaf(x.z, w.z, x.w * w.w)));
}

// ---- K0: bounds + weight conversions + proj transpose (one launch)
__global__ __launch_bounds__(256) void k_prep(
    const int* __restrict__ seg, const float* __restrict__ w_ih,
    const float* __restrict__ w_hh, const float* __restrict__ proj_w,
    int* __restrict__ start, u16* __restrict__ wihbf, u16* __restrict__ whhbf,
    u16* __restrict__ whhlo, u16* __restrict__ pwtbf) {
  __shared__ float tl[32][33];
  const int b = blockIdx.x, tid = threadIdx.x;
  const int gtid = b * 256 + tid;  // 0..262143
  {
    const int v = gtid;
    const int s = seg[v];
    if (v == 0) {
      for (int g = 0; g <= s; ++g) start[g] = 0;
    } else {
      const int p = seg[v - 1];
      for (int g = p + 1; g <= s; ++g) start[g] = v;
    }
    if (v == V_NODES - 1)
      for (int g = s + 1; g <= NGRAPH; ++g) start[g] = V_NODES;
  }
  {
    const int nchunk = TSTEPS * 768 * FD / 4;  // 98304
    if (gtid < nchunk) {
      const float4 x = ((const float4*)w_ih)[gtid];
      uint2 u; u.x = pkbf(x.x, x.y); u.y = pkbf(x.z, x.w);
      ((uint2*)wihbf)[gtid] = u;
      const float4 y = ((const float4*)w_hh)[gtid];
      const u16 h0 = f2bf(y.x), h1 = f2bf(y.y), h2 = f2bf(y.z), h3 = f2bf(y.w);
      uint2 hi_, lo_;
      hi_.x = (unsigned)h0 | ((unsigned)h1 << 16);
      hi_.y = (unsigned)h2 | ((unsigned)h3 << 16);
      lo_.x = pkbf(y.x - bf2f(h0), y.y - bf2f(h1));
      lo_.y = pkbf(y.z - bf2f(h2), y.w - bf2f(h3));
      ((uint2*)whhbf)[gtid] = hi_;
      ((uint2*)whhlo)[gtid] = lo_;
    }
  }
  if (b < 2 * 64) {  // proj_w [k][n] -> bf16 [n][k]
    const int t = b >> 6, tile = b & 63, bx = tile & 7, by = tile >> 3;
    const int tx = tid & 31, ty = tid >> 5;  // 32 x 8
    const float* S = proj_w + (size_t)t * FD * FD;
    u16* D = pwtbf + (size_t)t * FD * FD;
#pragma unroll
    for (int i = 0; i < 32; i += 8)
      tl[ty + i][tx] = S[(size_t)(by * 32 + ty + i) * FD + bx * 32 + tx];
    __syncthreads();
#pragma unroll
    for (int i = 0; i < 32; i += 8)
      D[(size_t)(bx * 32 + ty + i) * FD + by * 32 + tx] = f2bf(tl[tx][ty + i]);
  }
}

// ---- K1: wave per graph (1024 blocks x 4 waves). Zero LDS, zero barriers.
// Lane owns 4 feats -> segsum entirely in registers; 8 rows in flight.
__global__ __launch_bounds__(256) void k_pass1(
    const float* __restrict__ nf, const int* __restrict__ start,
    const float* __restrict__ logit_w, float* __restrict__ gf,
    u16* __restrict__ nbf, float* __restrict__ d0, float* __restrict__ d1) {
  const int wv = threadIdx.x >> 6, lane = threadIdx.x & 63;
  const int g = blockIdx.x * 4 + wv;
  const int s = start[g], e = start[g + 1];
  const float4 wA = ((const float4*)(logit_w + FD))[lane];
  const float4 wB = ((const float4*)(logit_w + 512 + FD))[lane];
  float4 ac = make_float4(0.f, 0.f, 0.f, 0.f);
  const float4* nfv = (const float4*)nf;
  int v = s;
  for (; v + 7 < e; v += 8) {
    float4 x[8];
#pragma unroll
    for (int r = 0; r < 8; ++r) x[r] = nfv[(size_t)(v + r) * 64 + lane];
#pragma unroll
    for (int r = 0; r < 8; ++r) {
      uint2 u; u.x = pkbf(x[r].x, x[r].y); u.y = pkbf(x[r].z, x[r].w);
      ((uint2*)(nbf + (size_t)(v + r) * FD))[lane] = u;
      ac.x += x[r].x; ac.y += x[r].y; ac.z += x[r].z; ac.w += x[r].w;
    }
    float dA[8], dB[8];
#pragma unroll
    for (int r = 0; r < 8; ++r) { dA[r] = dot4(x[r], wA); dB[r] = dot4(x[r], wB); }
#pragma unroll
    for (int off = 1; off < 64; off <<= 1) {     // 16 interleaved trees
#pragma unroll
      for (int r = 0; r < 8; ++r) {
        dA[r] += __shfl_xor(dA[r], off, 64);
        dB[r] += __shfl_xor(dB[r], off, 64);
      }
    }
    if (lane < 8) d0[v + lane] = dA[0], d0[v + lane] = dA[lane];
    if (lane == 0) {
#pragma unroll
      for (int r = 0; r < 8; ++r) { d0[v + r] = dA[r]; d1[v + r] = dB[r]; }
    }
  }
  for (; v < e; ++v) {
    const float4 x = nfv[(size_t)v * 64 + lane];
    uint2 u; u.x = pkbf(x.x, x.y); u.y = pkbf(x.z, x.w);
    ((uint2*)(nbf + (size_t)v * FD))[lane] = u;
    ac.x += x.x; ac.y += x.y; ac.z += x.z; ac.w += x.w;
    float dA = dot4(x, wA), dB = dot4(x, wB);
#pragma unroll
    for (int off = 1; off < 64; off <<= 1) {
      dA += __shfl_xor(dA, off, 64); dB += __shfl_xor(dB, off, 64);
    }
    if (lane == 0) { d0[v] = dA; d1[v] = dB; }
  }
  ((float4*)(gf + (size_t)g * FD))[lane] = ac;
}

// ---- K2: time loop. GP=16 graphs/block, 256 blocks, 16 waves/block.
// One wave per graph; full 16-row MFMA tiles; GRU fused in gate-GEMM epilogue;
// final gf store folded into t=1 epilogue.
__global__ __launch_bounds__(SB, 4) void k_steps(
    const int* __restrict__ start, const float* __restrict__ logit_w,
    const float* __restrict__ logit_b, const float* __restrict__ proj_b,
    const float* __restrict__ b_ih, const float* __restrict__ b_hh,
    const u16* __restrict__ nbf, const float* __restrict__ d0,
    const float* __restrict__ d1, float* __restrict__ gf_out,
    const u16* __restrict__ wihbf, const u16* __restrict__ whhbf,
    const u16* __restrict__ whhlo, const u16* __restrict__ pwtbf) {
  __shared__ __align__(16) float gf_s[GP][FD];     // 16K: h lives here all kernel
  __shared__ __align__(16) float ew[EWCAP];        // 10K: softmax weights
  __shared__ __align__(16) u16 wns_s[GP * RS];     // 8448B each; all 16 rows real
  __shared__ __align__(16) u16 ctx_s[GP * RS];
  __shared__ __align__(16) u16 hhi_s[GP * RS];
  __shared__ __align__(16) u16 hlo_s[GP * RS];

  const int b = blockIdx.x, tid = threadIdx.x;
  const int wv = tid >> 6, lane = tid & 63;        // 16 waves, wave wv owns graph g0+wv
  const int half = lane >> 5, sl = lane & 31;      // two 32-lane halves per wave
  const int g0 = b * GP;
  const int g = g0 + wv;
  const int vs = start[g0];
  const int s = start[g], e = start[g + 1];

  // load h into LDS (one float4 per thread: GP*FD/4 == SB)
  ((float4*)gf_s)[tid] = ((const float4*)(gf_out + (size_t)g0 * FD))[tid];
  __syncthreads();

#pragma unroll
  for (int t = 0; t < TSTEPS; ++t) {
    // ---- (A) h -> bf16 hi/lo in LDS
    for (int i = tid; i < GP * FD; i += SB) {
      const float x = gf_s[i >> 8][i & 255];
      const u16 hb = f2bf(x);
      hhi_s[(i >> 8) * RS + (i & 255)] = hb;
      hlo_s[(i >> 8) * RS + (i & 255)] = f2bf(x - bf2f(hb));
    }
    // ---- (B) softmax weights (full wave) + wsum stream -> wns_s
    {
      const float lb = logit_b[t];
      const float* dt = t ? d1 : d0;
      const float4 h4 = ((const float4*)&gf_s[wv][0])[lane];
      const float4 w4 = ((const float4*)(logit_w + (size_t)t * 512))[lane];
      float c = fmaf(fmaxf(h4.x, 0.f), w4.x, fmaf(fmaxf(h4.y, 0.f), w4.y,
                fmaf(fmaxf(h4.z, 0.f), w4.z, fmaxf(h4.w, 0.f) * w4.w)));
#pragma unroll
      for (int off = 1; off < 64; off <<= 1) c += __shfl_xor(c, off, 64);
      float m = -1e30f;
      for (int v2 = s + lane; v2 < e; v2 += 64) {
        const float z = softplus2(c + dt[v2] + lb);
        ew[v2 - vs] = z;
        m = fmaxf(m, z);
      }
#pragma unroll
      for (int off = 1; off < 64; off <<= 1) m = fmaxf(m, __shfl_xor(m, off, 64));
      float ls = 0.f;
      for (int v2 = s + lane; v2 < e; v2 += 64) {
        const float ez = __expf(ew[v2 - vs] - m);
        ew[v2 - vs] = ez;
        ls += ez;
      }
#pragma unroll
      for (int off = 1; off < 64; off <<= 1) ls += __shfl_xor(ls, off, 64);
      const float inv = (e > s) ? 1.0f / ls : 0.f;
      for (int v2 = s + lane; v2 < e; v2 += 64) ew[v2 - vs] *= inv;
      // weighted sum: halves take alternating rows, 8 rows in flight per half
      float acc[8];
#pragma unroll
      for (int j = 0; j < 8; ++j) acc[j] = 0.f;
      int v = s + half;
      for (; v + 14 < e; v += 16) {
        uint4 u[8];
#pragma unroll
        for (int r = 0; r < 8; ++r)
          u[r] = ((const uint4*)(nbf + (size_t)(v + 2 * r) * FD))[sl];
#pragma unroll
        for (int r = 0; r < 8; ++r) {
          const float a = ew[v + 2 * r - vs];
          acc[0] = fmaf(a, bf2f((u16)(u[r].x & 0xffff)), acc[0]);
          acc[1] = fmaf(a, bf2f((u16)(u[r].x >> 16)),    acc[1]);
          acc[2] = fmaf(a, bf2f((u16)(u[r].y & 0xffff)), acc[2]);
          acc[3] = fmaf(a, bf2f((u16)(u[r].y >> 16)),    acc[3]);
          acc[4] = fmaf(a, bf2f((u16)(u[r].z & 0xffff)), acc[4]);
          acc[5] = fmaf(a, bf2f((u16)(u[r].z >> 16)),    acc[5]);
          acc[6] = fmaf(a, bf2f((u16)(u[r].w & 0xffff)), acc[6]);
          acc[7] = fmaf(a, bf2f((u16)(u[r].w >> 16)),    acc[7]);
        }
      }
      for (; v < e; v += 2) {
        const uint4 u0 = ((const uint4*)(nbf + (size_t)v * FD))[sl];
        const float a0 = ew[v - vs];
        acc[0] = fmaf(a0, bf2f((u16)(u0.x & 0xffff)), acc[0]);
        acc[1] = fmaf(a0, bf2f((u16)(u0.x >> 16)),    acc[1]);
        acc[2] = fmaf(a0, bf2f((u16)(u0.y & 0xffff)), acc[2]);
        acc[3] = fmaf(a0, bf2f((u16)(u0.y >> 16)),    acc[3]);
        acc[4] = fmaf(a0, bf2f((u16)(u0.z & 0xffff)), acc[4]);
        acc[5] = fmaf(a0, bf2f((u16)(u0.z >> 16)),    acc[5]);
        acc[6] = fmaf(a0, bf2f((u16)(u0.w & 0xffff)), acc[6]);
        acc[7] = fmaf(a0, bf2f((u16)(u0.w >> 16)),    acc[7]);
      }
#pragma unroll
      for (int j = 0; j < 8; ++j) acc[j] += __shfl_xor(acc[j], 32, 64);
      if (half == 0) {
        uint4 w;
        w.x = pkbf(acc[0], acc[1]); w.y = pkbf(acc[2], acc[3]);
        w.z = pkbf(acc[4], acc[5]); w.w = pkbf(acc[6], acc[7]);
        *(uint4*)(wns_s + wv * RS + sl * 8) = w;
      }
    }
    __syncthreads();
    // ---- (C) ctx = elu(wns @ proj_w^T + proj_b); 16 tiles, 1/wave
    {
      const int r = lane & 15, q = lane >> 4;
      const u16* xp = wns_s + r * RS + q * 8;
      const u16* wp = pwtbf + (size_t)t * FD * FD + (size_t)(wv * 16 + r) * FD + q * 8;
      f32x4 a4 = {0.f, 0.f, 0.f, 0.f};
#pragma unroll
      for (int kt = 0; kt < 8; ++kt) {
        const short8 av = *(const short8*)(xp + kt * 32);
        const short8 bv = *(const short8*)(wp + kt * 32);
        a4 = __builtin_amdgcn_mfma_f32_16x16x32_bf16(av, bv, a4, 0, 0, 0);
      }
      const int gcol = wv * 16 + r;
      const float bs = proj_b[t * FD + gcol];
#pragma unroll
      for (int i = 0; i < 4; ++i) {
        float vv = a4[i] + bs;
        vv = (vv > 0.0f) ? vv : expm1f(vv);
        ctx_s[(q * 4 + i) * RS + gcol] = f2bf(vv);
      }
    }
    __syncthreads();
    // ---- (D) gate GEMMs + GRU fused in epilogue; wave owns 1 col-tile of 16
    {
      const int r = lane & 15, q = lane >> 4;
      const u16* xi = ctx_s + r * RS + q * 8;
      const u16* xh = hhi_s + r * RS + q * 8;
      const u16* xl = hlo_s + r * RS + q * 8;
      const u16* wih_t = wihbf + (size_t)t * 768 * FD;
      const u16* whh_t = whhbf + (size_t)t * 768 * FD;
      const u16* whl_t = whhlo + (size_t)t * 768 * FD;
      auto gpair = [&](const u16* wi, const u16* wh, const u16* wl,
                       f32x4& ai, f32x4& ah) {
#pragma unroll
        for (int kt = 0; kt < 8; ++kt) {
          const short8 aiv = *(const short8*)(xi + kt * 32);
          const short8 bi  = *(const short8*)(wi + kt * 32);
          ai = __builtin_amdgcn_mfma_f32_16x16x32_bf16(aiv, bi, ai, 0, 0, 0);
          const short8 xhh = *(const short8*)(xh + kt * 32);
          const short8 xll = *(const short8*)(xl + kt * 32);
          const short8 bh  = *(const short8*)(wh + kt * 32);
          const short8 bl  = *(const short8*)(wl + kt * 32);
          ah = __builtin_amdgcn_mfma_f32_16x16x32_bf16(xhh, bh, ah, 0, 0, 0);
          ah = __builtin_amdgcn_mfma_f32_16x16x32_bf16(xll, bh, ah, 0, 0, 0);
          ah = __builtin_amdgcn_mfma_f32_16x16x32_bf16(xhh, bl, ah, 0, 0, 0);
        }
      };
      const int col = wv * 16 + r;                // 0..255
      float rr[4], zz[4];
      {
        f32x4 ai = {0.f,0.f,0.f,0.f}, ah = {0.f,0.f,0.f,0.f};
        gpair(wih_t + (size_t)col * FD + q * 8,
              whh_t + (size_t)col * FD + q * 8,
              whl_t + (size_t)col * FD + q * 8, ai, ah);
        const float bi_ = b_ih[t * 768 + col], bh_ = b_hh[t * 768 + col];
#pragma unroll
        for (int i = 0; i < 4; ++i)
          rr[i] = 1.f / (1.f + __expf(-(ai[i] + bi_ + ah[i] + bh_)));
      }
      {
        f32x4 ai = {0.f,0.f,0.f,0.f}, ah = {0.f,0.f,0.f,0.f};
        gpair(wih_t + (size_t)(256 + col) * FD + q * 8,
              whh_t + (size_t)(256 + col) * FD + q * 8,
              whl_t + (size_t)(256 + col) * FD + q * 8, ai, ah);
        const float bi_ = b_ih[t * 768 + 256 + col], bh_ = b_hh[t * 768 + 256 + col];
#pragma unroll
        for (int i = 0; i < 4; ++i)
          zz[i] = 1.f / (1.f + __expf(-(ai[i] + bi_ + ah[i] + bh_)));
      }
      {
        f32x4 ai = {0.f,0.f,0.f,0.f}, ah = {0.f,0.f,0.f,0.f};
        gpair(wih_t + (size_t)(512 + col) * FD + q * 8,
              whh_t + (size_t)(512 + col) * FD + q * 8,
              whl_t + (size_t)(512 + col) * FD + q * 8, ai, ah);
        const float bi_ = b_ih[t * 768 + 512 + col], bh_ = b_hh[t * 768 + 512 + col];
#pragma unroll
        for (int i = 0; i < 4; ++i) {
          const int row = q * 4 + i;              // all 16 rows are real graphs
          const float nn = tanhf(ai[i] + bi_ + rr[i] * (ah[i] + bh_));
          const float hnew = (1.f - zz[i]) * nn + zz[i] * gf_s[row][col];
          if (t == TSTEPS - 1) {
            gf_out[(size_t)(g0 + row) * FD + col] = hnew;  // final store, fused
          } else {
            gf_s[row][col] = hnew;
          }
        }
      }
    }
    if (t != TSTEPS - 1) __syncthreads();
  }
}

extern "C" void kernel_launch(void* const* d_in, const int* in_sizes, int n_in,
                              void* d_out, int out_size, void* d_ws, size_t ws_size,
                              hipStream_t stream) {
  const float* node    = (const float*)d_in[0];
  const int*   seg     = (const int*)d_in[1];
  const float* logit_w = (const float*)d_in[3];
  const float* logit_b = (const float*)d_in[4];
  const float* proj_w  = (const float*)d_in[5];
  const float* proj_b  = (const float*)d_in[6];
  const float* w_ih    = (const float*)d_in[7];
  const float* w_hh    = (const float*)d_in[8];
  const float* b_ih    = (const float*)d_in[9];
  const float* b_hh    = (const float*)d_in[10];
  float* gfeats = (float*)d_out;

  char* p = (char*)d_ws;
  int* start   = (int*)p;   p += (((NGRAPH + 1) * sizeof(int)) + 255) & ~(size_t)255;
  u16* nbf     = (u16*)p;   p += (size_t)V_NODES * FD * 2;
  float* d0    = (float*)p; p += (size_t)V_NODES * 4;
  float* d1    = (float*)p; p += (size_t)V_NODES * 4;
  u16* wihbf   = (u16*)p;   p += (size_t)TSTEPS * 768 * FD * 2;
  u16* whhbf   = (u16*)p;   p += (size_t)TSTEPS * 768 * FD * 2;
  u16* whhlo   = (u16*)p;   p += (size_t)TSTEPS * 768 * FD * 2;
  u16* pwtbf   = (u16*)p;   p += (size_t)TSTEPS * FD * FD * 2;
  (void)ws_size; (void)in_sizes; (void)n_in; (void)out_size;

  k_prep<<<dim3(V_NODES / 256), dim3(256), 0, stream>>>(
      seg, w_ih, w_hh, proj_w, start, wihbf, whhbf, whhlo, pwtbf);
  k_pass1<<<dim3(NGRAPH / 4), dim3(256), 0, stream>>>(
      node, start, logit_w, gfeats, nbf, d0, d1);
  k_steps<<<dim3(NGRAPH / GP), dim3(SB), 0, stream>>>(
      start, logit_w, logit_b, proj_b, b_ih, b_hh, nbf, d0, d1,
      gfeats, wihbf, whhbf, whhlo, pwtbf);
}

// Round 5
// 543.293 us; speedup vs baseline: 1.0063x; 1.0063x over previous
//
#include <hip/hip_runtime.h>
#include <hip/hip_bf16.h>
#include <math.h>

#define V_NODES 262144
#define NGRAPH  4096
#define FD      256
#define TSTEPS  2
#define GP      16     // graphs per k_steps block (one wave per graph)
#define SB      1024   // k_steps block size: 16 waves
#define RS      264    // padded LDS row stride (u16) — 528B = 33*16B, +4-bank skew
#define EWCAP   2560   // max nodes per GP-graph block (mean 1024, sigma ~32)

typedef unsigned short u16;
typedef __attribute__((ext_vector_type(8))) short short8;
typedef __attribute__((ext_vector_type(4))) float f32x4;

__device__ __forceinline__ float bf2f(u16 u) {
  union { unsigned int i; float f; } x; x.i = ((unsigned int)u) << 16; return x.f;
}
__device__ __forceinline__ u16 f2bf(float f) {
  union { unsigned int i; float f; } x; x.f = f;
  unsigned int r = x.i + 0x7FFFu + ((x.i >> 16) & 1u);
  return (u16)(r >> 16);
}
__device__ __forceinline__ unsigned int pkbf(float a, float b) {
  return (unsigned int)f2bf(a) | ((unsigned int)f2bf(b) << 16);
}
__device__ __forceinline__ float softplus2(float x) {
  return fmaxf(x, 0.0f) + log1pf(__expf(-fabsf(x))) - 0.69314718056f;
}
__device__ __forceinline__ float dot4(const float4 x, const float4 w) {
  return fmaf(x.x, w.x, fmaf(x.y, w.y, fmaf(x.z, w.z, x.w * w.w)));
}

// ---- K0: bounds + weight conversions + proj transpose (one launch)
__global__ __launch_bounds__(256) void k_prep(
    const int* __restrict__ seg, const float* __restrict__ w_ih,
    const float* __restrict__ w_hh, const float* __restrict__ proj_w,
    int* __restrict__ start, u16* __restrict__ wihbf, u16* __restrict__ whhbf,
    u16* __restrict__ whhlo, u16* __restrict__ pwtbf) {
  __shared__ float tl[32][33];
  const int b = blockIdx.x, tid = threadIdx.x;
  const int gtid = b * 256 + tid;  // 0..262143
  {
    const int v = gtid;
    const int s = seg[v];
    if (v == 0) {
      for (int g = 0; g <= s; ++g) start[g] = 0;
    } else {
      const int p = seg[v - 1];
      for (int g = p + 1; g <= s; ++g) start[g] = v;
    }
    if (v == V_NODES - 1)
      for (int g = s + 1; g <= NGRAPH; ++g) start[g] = V_NODES;
  }
  {
    const int nchunk = TSTEPS * 768 * FD / 4;  // 98304
    if (gtid < nchunk) {
      const float4 x = ((const float4*)w_ih)[gtid];
      uint2 u; u.x = pkbf(x.x, x.y); u.y = pkbf(x.z, x.w);
      ((uint2*)wihbf)[gtid] = u;
      const float4 y = ((const float4*)w_hh)[gtid];
      const u16 h0 = f2bf(y.x), h1 = f2bf(y.y), h2 = f2bf(y.z), h3 = f2bf(y.w);
      uint2 hi_, lo_;
      hi_.x = (unsigned)h0 | ((unsigned)h1 << 16);
      hi_.y = (unsigned)h2 | ((unsigned)h3 << 16);
      lo_.x = pkbf(y.x - bf2f(h0), y.y - bf2f(h1));
      lo_.y = pkbf(y.z - bf2f(h2), y.w - bf2f(h3));
      ((uint2*)whhbf)[gtid] = hi_;
      ((uint2*)whhlo)[gtid] = lo_;
    }
  }
  if (b < 2 * 64) {  // proj_w [k][n] -> bf16 [n][k]
    const int t = b >> 6, tile = b & 63, bx = tile & 7, by = tile >> 3;
    const int tx = tid & 31, ty = tid >> 5;  // 32 x 8
    const float* S = proj_w + (size_t)t * FD * FD;
    u16* D = pwtbf + (size_t)t * FD * FD;
#pragma unroll
    for (int i = 0; i < 32; i += 8)
      tl[ty + i][tx] = S[(size_t)(by * 32 + ty + i) * FD + bx * 32 + tx];
    __syncthreads();
#pragma unroll
    for (int i = 0; i < 32; i += 8)
      D[(size_t)(bx * 32 + ty + i) * FD + by * 32 + tx] = f2bf(tl[tx][ty + i]);
  }
}

// ---- K1: wave per graph (1024 blocks x 4 waves). Zero LDS, zero barriers.
// Lane owns 4 feats -> segsum entirely in registers; 8 rows in flight.
// NOTE: no runtime indexing of dA/dB (would force scratch — rule #20).
__global__ __launch_bounds__(256) void k_pass1(
    const float* __restrict__ nf, const int* __restrict__ start,
    const float* __restrict__ logit_w, float* __restrict__ gf,
    u16* __restrict__ nbf, float* __restrict__ d0, float* __restrict__ d1) {
  const int wv = threadIdx.x >> 6, lane = threadIdx.x & 63;
  const int g = blockIdx.x * 4 + wv;
  const int s = start[g], e = start[g + 1];
  const float4 wA = ((const float4*)(logit_w + FD))[lane];
  const float4 wB = ((const float4*)(logit_w + 512 + FD))[lane];
  float4 ac = make_float4(0.f, 0.f, 0.f, 0.f);
  const float4* nfv = (const float4*)nf;
  int v = s;
  for (; v + 7 < e; v += 8) {
    float4 x[8];
#pragma unroll
    for (int r = 0; r < 8; ++r) x[r] = nfv[(size_t)(v + r) * 64 + lane];
#pragma unroll
    for (int r = 0; r < 8; ++r) {
      uint2 u; u.x = pkbf(x[r].x, x[r].y); u.y = pkbf(x[r].z, x[r].w);
      ((uint2*)(nbf + (size_t)(v + r) * FD))[lane] = u;
      ac.x += x[r].x; ac.y += x[r].y; ac.z += x[r].z; ac.w += x[r].w;
    }
    float dA[8], dB[8];
#pragma unroll
    for (int r = 0; r < 8; ++r) { dA[r] = dot4(x[r], wA); dB[r] = dot4(x[r], wB); }
#pragma unroll
    for (int off = 1; off < 64; off <<= 1) {     // 16 interleaved trees
#pragma unroll
      for (int r = 0; r < 8; ++r) {
        dA[r] += __shfl_xor(dA[r], off, 64);
        dB[r] += __shfl_xor(dB[r], off, 64);
      }
    }
    if (lane == 0) {
#pragma unroll
      for (int r = 0; r < 8; ++r) { d0[v + r] = dA[r]; d1[v + r] = dB[r]; }
    }
  }
  for (; v < e; ++v) {
    const float4 x = nfv[(size_t)v * 64 + lane];
    uint2 u; u.x = pkbf(x.x, x.y); u.y = pkbf(x.z, x.w);
    ((uint2*)(nbf + (size_t)v * FD))[lane] = u;
    ac.x += x.x; ac.y += x.y; ac.z += x.z; ac.w += x.w;
    float dA = dot4(x, wA), dB = dot4(x, wB);
#pragma unroll
    for (int off = 1; off < 64; off <<= 1) {
      dA += __shfl_xor(dA, off, 64); dB += __shfl_xor(dB, off, 64);
    }
    if (lane == 0) { d0[v] = dA; d1[v] = dB; }
  }
  ((float4*)(gf + (size_t)g * FD))[lane] = ac;
}

// ---- K2: time loop. GP=16 graphs/block, 256 blocks, 16 waves/block.
// One wave per graph; full 16-row MFMA tiles; GRU fused in gate-GEMM epilogue;
// final gf store folded into t=1 epilogue.
__global__ __launch_bounds__(SB, 4) void k_steps(
    const int* __restrict__ start, const float* __restrict__ logit_w,
    const float* __restrict__ logit_b, const float* __restrict__ proj_b,
    const float* __restrict__ b_ih, const float* __restrict__ b_hh,
    const u16* __restrict__ nbf, const float* __restrict__ d0,
    const float* __restrict__ d1, float* __restrict__ gf_out,
    const u16* __restrict__ wihbf, const u16* __restrict__ whhbf,
    const u16* __restrict__ whhlo, const u16* __restrict__ pwtbf) {
  __shared__ __align__(16) float gf_s[GP][FD];     // 16K: h lives here all kernel
  __shared__ __align__(16) float ew[EWCAP];        // 10K: softmax weights
  __shared__ __align__(16) u16 wns_s[GP * RS];     // 8448B each; all 16 rows real
  __shared__ __align__(16) u16 ctx_s[GP * RS];
  __shared__ __align__(16) u16 hhi_s[GP * RS];
  __shared__ __align__(16) u16 hlo_s[GP * RS];

  const int b = blockIdx.x, tid = threadIdx.x;
  const int wv = tid >> 6, lane = tid & 63;        // 16 waves, wave wv owns graph g0+wv
  const int half = lane >> 5, sl = lane & 31;      // two 32-lane halves per wave
  const int g0 = b * GP;
  const int g = g0 + wv;
  const int vs = start[g0];
  const int s = start[g], e = start[g + 1];

  // load h into LDS (one float4 per thread: GP*FD/4 == SB)
  ((float4*)gf_s)[tid] = ((const float4*)(gf_out + (size_t)g0 * FD))[tid];
  __syncthreads();

#pragma unroll
  for (int t = 0; t < TSTEPS; ++t) {
    // ---- (A) h -> bf16 hi/lo in LDS
    for (int i = tid; i < GP * FD; i += SB) {
      const float x = gf_s[i >> 8][i & 255];
      const u16 hb = f2bf(x);
      hhi_s[(i >> 8) * RS + (i & 255)] = hb;
      hlo_s[(i >> 8) * RS + (i & 255)] = f2bf(x - bf2f(hb));
    }
    // ---- (B) softmax weights (full wave) + wsum stream -> wns_s
    {
      const float lb = logit_b[t];
      const float* dt = t ? d1 : d0;
      const float4 h4 = ((const float4*)&gf_s[wv][0])[lane];
      const float4 w4 = ((const float4*)(logit_w + (size_t)t * 512))[lane];
      float c = fmaf(fmaxf(h4.x, 0.f), w4.x, fmaf(fmaxf(h4.y, 0.f), w4.y,
                fmaf(fmaxf(h4.z, 0.f), w4.z, fmaxf(h4.w, 0.f) * w4.w)));
#pragma unroll
      for (int off = 1; off < 64; off <<= 1) c += __shfl_xor(c, off, 64);
      float m = -1e30f;
      for (int v2 = s + lane; v2 < e; v2 += 64) {
        const float z = softplus2(c + dt[v2] + lb);
        ew[v2 - vs] = z;
        m = fmaxf(m, z);
      }
#pragma unroll
      for (int off = 1; off < 64; off <<= 1) m = fmaxf(m, __shfl_xor(m, off, 64));
      float ls = 0.f;
      for (int v2 = s + lane; v2 < e; v2 += 64) {
        const float ez = __expf(ew[v2 - vs] - m);
        ew[v2 - vs] = ez;
        ls += ez;
      }
#pragma unroll
      for (int off = 1; off < 64; off <<= 1) ls += __shfl_xor(ls, off, 64);
      const float inv = (e > s) ? 1.0f / ls : 0.f;
      for (int v2 = s + lane; v2 < e; v2 += 64) ew[v2 - vs] *= inv;
      // weighted sum: halves take alternating rows, 8 rows in flight per half
      float acc[8];
#pragma unroll
      for (int j = 0; j < 8; ++j) acc[j] = 0.f;
      int v = s + half;
      for (; v + 14 < e; v += 16) {
        uint4 u[8];
#pragma unroll
        for (int r = 0; r < 8; ++r)
          u[r] = ((const uint4*)(nbf + (size_t)(v + 2 * r) * FD))[sl];
#pragma unroll
        for (int r = 0; r < 8; ++r) {
          const float a = ew[v + 2 * r - vs];
          acc[0] = fmaf(a, bf2f((u16)(u[r].x & 0xffff)), acc[0]);
          acc[1] = fmaf(a, bf2f((u16)(u[r].x >> 16)),    acc[1]);
          acc[2] = fmaf(a, bf2f((u16)(u[r].y & 0xffff)), acc[2]);
          acc[3] = fmaf(a, bf2f((u16)(u[r].y >> 16)),    acc[3]);
          acc[4] = fmaf(a, bf2f((u16)(u[r].z & 0xffff)), acc[4]);
          acc[5] = fmaf(a, bf2f((u16)(u[r].z >> 16)),    acc[5]);
          acc[6] = fmaf(a, bf2f((u16)(u[r].w & 0xffff)), acc[6]);
          acc[7] = fmaf(a, bf2f((u16)(u[r].w >> 16)),    acc[7]);
        }
      }
      for (; v < e; v += 2) {
        const uint4 u0 = ((const uint4*)(nbf + (size_t)v * FD))[sl];
        const float a0 = ew[v - vs];
        acc[0] = fmaf(a0, bf2f((u16)(u0.x & 0xffff)), acc[0]);
        acc[1] = fmaf(a0, bf2f((u16)(u0.x >> 16)),    acc[1]);
        acc[2] = fmaf(a0, bf2f((u16)(u0.y & 0xffff)), acc[2]);
        acc[3] = fmaf(a0, bf2f((u16)(u0.y >> 16)),    acc[3]);
        acc[4] = fmaf(a0, bf2f((u16)(u0.z & 0xffff)), acc[4]);
        acc[5] = fmaf(a0, bf2f((u16)(u0.z >> 16)),    acc[5]);
        acc[6] = fmaf(a0, bf2f((u16)(u0.w & 0xffff)), acc[6]);
        acc[7] = fmaf(a0, bf2f((u16)(u0.w >> 16)),    acc[7]);
      }
#pragma unroll
      for (int j = 0; j < 8; ++j) acc[j] += __shfl_xor(acc[j], 32, 64);
      if (half == 0) {
        uint4 w;
        w.x = pkbf(acc[0], acc[1]); w.y = pkbf(acc[2], acc[3]);
        w.z = pkbf(acc[4], acc[5]); w.w = pkbf(acc[6], acc[7]);
        *(uint4*)(wns_s + wv * RS + sl * 8) = w;
      }
    }
    __syncthreads();
    // ---- (C) ctx = elu(wns @ proj_w^T + proj_b); 16 tiles, 1/wave
    {
      const int r = lane & 15, q = lane >> 4;
      const u16* xp = wns_s + r * RS + q * 8;
      const u16* wp = pwtbf + (size_t)t * FD * FD + (size_t)(wv * 16 + r) * FD + q * 8;
      f32x4 a4 = {0.f, 0.f, 0.f, 0.f};
#pragma unroll
      for (int kt = 0; kt < 8; ++kt) {
        const short8 av = *(const short8*)(xp + kt * 32);
        const short8 bv = *(const short8*)(wp + kt * 32);
        a4 = __builtin_amdgcn_mfma_f32_16x16x32_bf16(av, bv, a4, 0, 0, 0);
      }
      const int gcol = wv * 16 + r;
      const float bs = proj_b[t * FD + gcol];
#pragma unroll
      for (int i = 0; i < 4; ++i) {
        float vv = a4[i] + bs;
        vv = (vv > 0.0f) ? vv : expm1f(vv);
        ctx_s[(q * 4 + i) * RS + gcol] = f2bf(vv);
      }
    }
    __syncthreads();
    // ---- (D) gate GEMMs + GRU fused in epilogue; wave owns 1 col-tile of 16
    {
      const int r = lane & 15, q = lane >> 4;
      const u16* xi = ctx_s + r * RS + q * 8;
      const u16* xh = hhi_s + r * RS + q * 8;
      const u16* xl = hlo_s + r * RS + q * 8;
      const u16* wih_t = wihbf + (size_t)t * 768 * FD;
      const u16* whh_t = whhbf + (size_t)t * 768 * FD;
      const u16* whl_t = whhlo + (size_t)t * 768 * FD;
      auto gpair = [&](const u16* wi, const u16* wh, const u16* wl,
                       f32x4& ai, f32x4& ah) {
#pragma unroll
        for (int kt = 0; kt < 8; ++kt) {
          const short8 aiv = *(const short8*)(xi + kt * 32);
          const short8 bi  = *(const short8*)(wi + kt * 32);
          ai = __builtin_amdgcn_mfma_f32_16x16x32_bf16(aiv, bi, ai, 0, 0, 0);
          const short8 xhh = *(const short8*)(xh + kt * 32);
          const short8 xll = *(const short8*)(xl + kt * 32);
          const short8 bh  = *(const short8*)(wh + kt * 32);
          const short8 bl  = *(const short8*)(wl + kt * 32);
          ah = __builtin_amdgcn_mfma_f32_16x16x32_bf16(xhh, bh, ah, 0, 0, 0);
          ah = __builtin_amdgcn_mfma_f32_16x16x32_bf16(xll, bh, ah, 0, 0, 0);
          ah = __builtin_amdgcn_mfma_f32_16x16x32_bf16(xhh, bl, ah, 0, 0, 0);
        }
      };
      const int col = wv * 16 + r;                // 0..255
      float rr[4], zz[4];
      {
        f32x4 ai = {0.f,0.f,0.f,0.f}, ah = {0.f,0.f,0.f,0.f};
        gpair(wih_t + (size_t)col * FD + q * 8,
              whh_t + (size_t)col * FD + q * 8,
              whl_t + (size_t)col * FD + q * 8, ai, ah);
        const float bi_ = b_ih[t * 768 + col], bh_ = b_hh[t * 768 + col];
#pragma unroll
        for (int i = 0; i < 4; ++i)
          rr[i] = 1.f / (1.f + __expf(-(ai[i] + bi_ + ah[i] + bh_)));
      }
      {
        f32x4 ai = {0.f,0.f,0.f,0.f}, ah = {0.f,0.f,0.f,0.f};
        gpair(wih_t + (size_t)(256 + col) * FD + q * 8,
              whh_t + (size_t)(256 + col) * FD + q * 8,
              whl_t + (size_t)(256 + col) * FD + q * 8, ai, ah);
        const float bi_ = b_ih[t * 768 + 256 + col], bh_ = b_hh[t * 768 + 256 + col];
#pragma unroll
        for (int i = 0; i < 4; ++i)
          zz[i] = 1.f / (1.f + __expf(-(ai[i] + bi_ + ah[i] + bh_)));
      }
      {
        f32x4 ai = {0.f,0.f,0.f,0.f}, ah = {0.f,0.f,0.f,0.f};
        gpair(wih_t + (size_t)(512 + col) * FD + q * 8,
              whh_t + (size_t)(512 + col) * FD + q * 8,
              whl_t + (size_t)(512 + col) * FD + q * 8, ai, ah);
        const float bi_ = b_ih[t * 768 + 512 + col], bh_ = b_hh[t * 768 + 512 + col];
#pragma unroll
        for (int i = 0; i < 4; ++i) {
          const int row = q * 4 + i;              // all 16 rows are real graphs
          const float nn = tanhf(ai[i] + bi_ + rr[i] * (ah[i] + bh_));
          const float hnew = (1.f - zz[i]) * nn + zz[i] * gf_s[row][col];
          if (t == TSTEPS - 1) {
            gf_out[(size_t)(g0 + row) * FD + col] = hnew;  // final store, fused
          } else {
            gf_s[row][col] = hnew;
          }
        }
      }
    }
    if (t != TSTEPS - 1) __syncthreads();
  }
}

extern "C" void kernel_launch(void* const* d_in, const int* in_sizes, int n_in,
                              void* d_out, int out_size, void* d_ws, size_t ws_size,
                              hipStream_t stream) {
  const float* node    = (const float*)d_in[0];
  const int*   seg     = (const int*)d_in[1];
  const float* logit_w = (const float*)d_in[3];
  const float* logit_b = (const float*)d_in[4];
  const float* proj_w  = (const float*)d_in[5];
  const float* proj_b  = (const float*)d_in[6];
  const float* w_ih    = (const float*)d_in[7];
  const float* w_hh    = (const float*)d_in[8];
  const float* b_ih    = (const float*)d_in[9];
  const float* b_hh    = (const float*)d_in[10];
  float* gfeats = (float*)d_out;

  char* p = (char*)d_ws;
  int* start   = (int*)p;   p += (((NGRAPH + 1) * sizeof(int)) + 255) & ~(size_t)255;
  u16* nbf     = (u16*)p;   p += (size_t)V_NODES * FD * 2;
  float* d0    = (float*)p; p += (size_t)V_NODES * 4;
  float* d1    = (float*)p; p += (size_t)V_NODES * 4;
  u16* wihbf   = (u16*)p;   p += (size_t)TSTEPS * 768 * FD * 2;
  u16* whhbf   = (u16*)p;   p += (size_t)TSTEPS * 768 * FD * 2;
  u16* whhlo   = (u16*)p;   p += (size_t)TSTEPS * 768 * FD * 2;
  u16* pwtbf   = (u16*)p;   p += (size_t)TSTEPS * FD * FD * 2;
  (void)ws_size; (void)in_sizes; (void)n_in; (void)out_size;

  k_prep<<<dim3(V_NODES / 256), dim3(256), 0, stream>>>(
      seg, w_ih, w_hh, proj_w, start, wihbf, whhbf, whhlo, pwtbf);
  k_pass1<<<dim3(NGRAPH / 4), dim3(256), 0, stream>>>(
      node, start, logit_w, gfeats, nbf, d0, d1);
  k_steps<<<dim3(NGRAPH / GP), dim3(SB), 0, stream>>>(
      start, logit_w, logit_b, proj_b, b_ih, b_hh, nbf, d0, d1,
      gfeats, wihbf, whhbf, whhlo, pwtbf);
}